// Round 2
// baseline (11423.303 us; speedup 1.0000x reference)
//
#include <hip/hip_runtime.h>
#include <hip/hip_bf16.h>

// LSTM: B=64, T=512, I=1024, H=1024. Persistent cooperative kernel.
// 128 blocks x 512 threads, 1 block/CU (LDS-bound ~146KB), all co-resident -> spin grid barrier.
// Each block owns 8 H-columns (x4 gates = 32 gate-cols). Wx/Wh slices in LDS (fp16, XOR-swizzled).
// h double-buffered in ws as fp16, via agent-scope (sc1/LLC) atomics -> no L2 staleness, no buffer_inv.
// Pipeline per step t: [x-waves: x-gemm(t+1)->regs  ||  h-waves: h-gemm(t)] -> reduce -> epilogue
//                      -> publish h[t] + commit x(t+1)->red -> grid barrier.

#define NB 128
#define NT 512
#define T_STEPS 512
#define HDIM 1024

typedef __attribute__((ext_vector_type(8))) _Float16 half8;
typedef __attribute__((ext_vector_type(4))) float f32x4;
typedef __attribute__((ext_vector_type(4))) float fvec4;

// ws layout (bytes)
#define HG_OFF 0                   // 2 x [64][1024] fp16 = 2*131072
#define CNT_OFF (2 * 131072)       // u32 barrier counter (own line)

// LDS layout (bytes)
#define LDS_W 0                            // [2 mats][32 cols][1024 k] fp16, swizzled = 131072
#define LDS_RED 131072                     // f32 [2 parts][64 rows][33] = 16896 (pad 33)
#define LDS_HST (131072 + 16896)           // ushort fp16 [64][8] = 1024
#define LDS_BIAS (131072 + 16896 + 1024)   // f32 [32]
#define LDS_TOT (131072 + 16896 + 1024 + 128)

__device__ __forceinline__ unsigned short f2h(float f) {
    _Float16 h = (_Float16)f;  // v_cvt_f16_f32, RNE
    unsigned short u;
    __builtin_memcpy(&u, &h, 2);
    return u;
}
__device__ __forceinline__ float sigm(float x) { return 1.f / (1.f + __expf(-x)); }
__device__ __forceinline__ float tanh_(float x) {
    float t = __expf(-2.f * fabsf(x));
    float r = (1.f - t) / (1.f + t);
    return copysignf(r, x);
}

// ---- x-part GEMM: 32 batch-rows (mhalf) x 32 gate-cols, K slice [k0,k0+512). A from global fp32 x.
__device__ __forceinline__ void gemm_x(const float* __restrict__ x, int t, int k0, int mhalf,
                                       int lane, const char* wlds, f32x4 acc[2][2]) {
    const int l15 = lane & 15, l4 = lane >> 4;
#pragma unroll 4
    for (int ks = 0; ks < 16; ++ks) {
        const int kk = k0 + ks * 32 + l4 * 8;  // multiple of 8
        half8 a[2];
#pragma unroll
        for (int mt = 0; mt < 2; ++mt) {
            const int row = mhalf * 32 + mt * 16 + l15;  // batch row (A-frag: row=l&15)
            const float* p = x + ((size_t)(row * T_STEPS + t)) * HDIM + kk;
            fvec4 v0 = *(const fvec4*)p;
            fvec4 v1 = *(const fvec4*)(p + 4);
            half8 av;
            av[0] = (_Float16)v0[0]; av[1] = (_Float16)v0[1];
            av[2] = (_Float16)v0[2]; av[3] = (_Float16)v0[3];
            av[4] = (_Float16)v1[0]; av[5] = (_Float16)v1[1];
            av[6] = (_Float16)v1[2]; av[7] = (_Float16)v1[3];
            a[mt] = av;
        }
        half8 b[2];
        const int g = kk >> 3;
#pragma unroll
        for (int nt = 0; nt < 2; ++nt) {
            const int col = nt * 16 + l15;
            const int gs = g ^ (col & 7);  // T2 XOR swizzle: ~2-way on ds_read_b128 (free, m136)
            b[nt] = *(const half8*)(wlds + col * 2048 + (gs << 4));
        }
#pragma unroll
        for (int mt = 0; mt < 2; ++mt)
#pragma unroll
            for (int nt = 0; nt < 2; ++nt)
                acc[mt][nt] = __builtin_amdgcn_mfma_f32_16x16x32_f16(a[mt], b[nt], acc[mt][nt], 0, 0, 0);
    }
}

// ---- h-part GEMM: A (fp16 h) from LLC via sc1 atomics. Preload ALL 64 loads up-front so the
// ~LLC latency is paid once (loads back-to-back, vmcnt drains naturally before first use).
__device__ __forceinline__ void gemm_h(const unsigned long long* hbuf, int k0, int mhalf, int lane,
                                       const char* wlds, f32x4 acc[2][2]) {
    const int l15 = lane & 15, l4 = lane >> 4;
    unsigned long long av[16][2][2];  // [ks][mt][2x u64] = 128 VGPRs, all indices compile-time
#pragma unroll
    for (int ks = 0; ks < 16; ++ks) {
        const int kk = k0 + ks * 32 + l4 * 8;
#pragma unroll
        for (int mt = 0; mt < 2; ++mt) {
            const int row = mhalf * 32 + mt * 16 + l15;
            unsigned long long* p = (unsigned long long*)(hbuf + ((row * 1024 + kk) >> 2));
            av[ks][mt][0] = __hip_atomic_load(p, __ATOMIC_RELAXED, __HIP_MEMORY_SCOPE_AGENT);
            av[ks][mt][1] = __hip_atomic_load(p + 1, __ATOMIC_RELAXED, __HIP_MEMORY_SCOPE_AGENT);
        }
    }
#pragma unroll
    for (int ks = 0; ks < 16; ++ks) {
        const int kk = k0 + ks * 32 + l4 * 8;
        const int g = kk >> 3;
        half8 b[2];
#pragma unroll
        for (int nt = 0; nt < 2; ++nt) {
            const int col = nt * 16 + l15;
            const int gs = g ^ (col & 7);
            b[nt] = *(const half8*)(wlds + 65536 + col * 2048 + (gs << 4));
        }
#pragma unroll
        for (int mt = 0; mt < 2; ++mt) {
            union { unsigned long long u[2]; half8 h; } cv;
            cv.u[0] = av[ks][mt][0];
            cv.u[1] = av[ks][mt][1];
#pragma unroll
            for (int nt = 0; nt < 2; ++nt)
                acc[mt][nt] = __builtin_amdgcn_mfma_f32_16x16x32_f16(cv.h, b[nt], acc[mt][nt], 0, 0, 0);
        }
    }
}

// C/D layout (m89): lane l, reg r -> row (l>>4)*4+r, col l&15.
__device__ __forceinline__ void acc_to_red(float* red, int part, int mhalf, int lane,
                                           const f32x4 acc[2][2], bool add) {
    const int l15 = lane & 15, l4 = lane >> 4;
#pragma unroll
    for (int mt = 0; mt < 2; ++mt)
#pragma unroll
        for (int nt = 0; nt < 2; ++nt)
#pragma unroll
            for (int r = 0; r < 4; ++r) {
                int row = mhalf * 32 + mt * 16 + l4 * 4 + r;
                int col = nt * 16 + l15;
                float* p = red + (part * 64 + row) * 33 + col;
                if (add) *p += acc[mt][nt][r];
                else     *p  = acc[mt][nt][r];
            }
}

__global__ __launch_bounds__(512, 2) void lstm_persistent(
    const float* __restrict__ x,
    const float* __restrict__ Wxi, const float* __restrict__ Whi, const float* __restrict__ bi,
    const float* __restrict__ Wxf, const float* __restrict__ Whf, const float* __restrict__ bfv,
    const float* __restrict__ Wxg, const float* __restrict__ Whg, const float* __restrict__ bg,
    const float* __restrict__ Wxo, const float* __restrict__ Who, const float* __restrict__ bo,
    float* __restrict__ out, char* __restrict__ ws) {
    __shared__ __align__(16) char smem[LDS_TOT];
    __shared__ int dead;

    const int tid = threadIdx.x, bid = blockIdx.x;
    const int lane = tid & 63, w = tid >> 6;
    const int mhalf = w & 1, kq = w >> 1;  // kq 0,1: x K-halves; 2,3: h K-halves

    unsigned long long* hg = (unsigned long long*)(ws + HG_OFF);  // u64 = 4 fp16
    unsigned* cnt = (unsigned*)(ws + CNT_OFF);

    float* red = (float*)(smem + LDS_RED);
    unsigned short* hst = (unsigned short*)(smem + LDS_HST);
    const float* bias = (const float*)(smem + LDS_BIAS);
    char* wlds = smem + LDS_W;

    if (tid == 0) dead = 0;

    // ---- init: stage weight slices -> LDS (fp16, swizzled col-major) ----
    {
        const float* WX[4] = {Wxi, Wxf, Wxg, Wxo};
        const float* WH[4] = {Whi, Whf, Whg, Who};
        const float* BB[4] = {bi, bfv, bg, bo};
        for (int e = tid; e < 65536; e += NT) {
            int s = e >> 15, col = (e >> 10) & 31, k = e & 1023;
            int gate = col >> 3, hc = col & 7;
            const float* W = (s == 0) ? WX[gate] : WH[gate];
            float v = W[(size_t)k * HDIM + bid * 8 + hc];
            int gs = (k >> 3) ^ (col & 7);
            *(unsigned short*)(wlds + s * 65536 + col * 2048 + (gs << 4) + (k & 7) * 2) = f2h(v);
        }
        if (tid < 32) {
            int gate = tid >> 3, hc = tid & 7;
            ((float*)(smem + LDS_BIAS))[tid] = BB[gate][bid * 8 + hc];
        }
        int g = bid * NT + tid;  // zero h buffer 0 (16384 u64 grid-wide; blocks 0..31)
        if (g < 16384)
            __hip_atomic_store(hg + g, 0ULL, __ATOMIC_RELAXED, __HIP_MEMORY_SCOPE_AGENT);
    }

    unsigned phase = 0;

    // Grid barrier. Leading __syncthreads: every wave drains vmcnt(0) -> its sc1 stores are in
    // LLC before tid0's RELEASE add. RELAXED spin -> no acquire fence -> no L2 invalidate, so x
    // and weight lines stay cached. Monotonic counter. Last arriver skips the spin.
#define GRID_BARRIER()                                                                             \
    do {                                                                                           \
        __syncthreads();                                                                           \
        if (tid == 0) {                                                                            \
            ++phase;                                                                               \
            unsigned tgt = phase * (unsigned)NB;                                                   \
            unsigned old = __hip_atomic_fetch_add(cnt, 1u, __ATOMIC_RELEASE,                       \
                                                  __HIP_MEMORY_SCOPE_AGENT);                       \
            if (old != tgt - 1) {                                                                  \
                int guard = 0;                                                                     \
                while (__hip_atomic_load(cnt, __ATOMIC_RELAXED, __HIP_MEMORY_SCOPE_AGENT) < tgt) { \
                    if (++guard > (1 << 20)) { dead = 1; break; }                                  \
                }                                                                                  \
            }                                                                                      \
        }                                                                                          \
        __syncthreads();                                                                           \
        if (dead) return;                                                                          \
    } while (0)

    GRID_BARRIER();  // weights/bias/h0 visible everywhere

    // pre-loop: x partials for t=0 -> red
    if (kq < 2) {
        f32x4 acc0[2][2] = {};
        gemm_x(x, 0, (kq & 1) * 512, mhalf, lane, wlds, acc0);
        acc_to_red(red, kq, mhalf, lane, acc0, false);
    }

    float creg = 0.f;
    const int erow = tid >> 3, ehc = tid & 7;

    for (int t = 0; t < T_STEPS; ++t) {
        // Phase 1 (concurrent): h-waves h-gemm(t) from buffer t&1; x-waves x-gemm(t+1) -> regs.
        f32x4 acch[2][2] = {};
        f32x4 accx[2][2] = {};
        if (kq >= 2) {
            gemm_h(hg + (size_t)(t & 1) * 16384, (kq & 1) * 512, mhalf, lane, wlds, acch);
        } else if (t + 1 < T_STEPS) {
            gemm_x(x, t + 1, (kq & 1) * 512, mhalf, lane, wlds, accx);
        }
        __syncthreads();  // red holds x(t) partials (committed last iter / pre-loop)
        if (kq >= 2) acc_to_red(red, kq - 2, mhalf, lane, acch, true);
        __syncthreads();

        // epilogue: one (batch-row, h-col) cell per thread; c stays fp32 in-register
        {
            float z[4];
#pragma unroll
            for (int gi = 0; gi < 4; ++gi) {
                int col = gi * 8 + ehc;
                z[gi] = red[(0 * 64 + erow) * 33 + col] + red[(1 * 64 + erow) * 33 + col] + bias[col];
            }
            float ig = sigm(z[0]), fg = sigm(z[1]), gv = tanh_(z[2]), og = sigm(z[3]);
            creg = fg * creg + ig * gv;
            float hn = og * tanh_(creg);
            hst[erow * 8 + ehc] = f2h(hn);
            if (t == T_STEPS - 1) {
                out[erow * HDIM + bid * 8 + ehc] = hn;            // h_T
                out[65536 + erow * HDIM + bid * 8 + ehc] = creg;  // c_T
            }
        }
        __syncthreads();  // hst ready; red dead

        if (t + 1 < T_STEPS) {
            // publish h[t] slice -> buffer (t+1)&1, LLC-direct (wave 0)
            if (tid < 64) {
                const unsigned long long* s = (const unsigned long long*)(hst + tid * 8);
                unsigned long long* d = hg + (size_t)((t + 1) & 1) * 16384 + tid * 256 + bid * 2;
                __hip_atomic_store(d, s[0], __ATOMIC_RELAXED, __HIP_MEMORY_SCOPE_AGENT);
                __hip_atomic_store(d + 1, s[1], __ATOMIC_RELAXED, __HIP_MEMORY_SCOPE_AGENT);
            }
            // commit x(t+1) partials -> red (red freed by the hst-ready sync above)
            if (kq < 2) acc_to_red(red, kq, mhalf, lane, accx, false);
            GRID_BARRIER();
        }
    }
#undef GRID_BARRIER
}

extern "C" void kernel_launch(void* const* d_in, const int* in_sizes, int n_in,
                              void* d_out, int out_size, void* d_ws, size_t ws_size,
                              hipStream_t stream) {
    const float* x   = (const float*)d_in[0];
    const float* Wii = (const float*)d_in[1];
    const float* Whi = (const float*)d_in[2];
    const float* bhi = (const float*)d_in[3];
    const float* Wif = (const float*)d_in[4];
    const float* Whf = (const float*)d_in[5];
    const float* bhf = (const float*)d_in[6];
    const float* Wig = (const float*)d_in[7];
    const float* Whg = (const float*)d_in[8];
    const float* bhg = (const float*)d_in[9];
    const float* Wio = (const float*)d_in[10];
    const float* Who = (const float*)d_in[11];
    const float* bho = (const float*)d_in[12];
    float* out = (float*)d_out;
    char* ws = (char*)d_ws;

    // ws is re-poisoned 0xAA before every timed launch: barrier counter must start at 0.
    hipMemsetAsync(ws + CNT_OFF, 0, 256, stream);
    lstm_persistent<<<dim3(NB), dim3(NT), 0, stream>>>(x, Wii, Whi, bhi, Wif, Whf, bhf,
                                                       Wig, Whg, bhg, Wio, Who, bho, out, ws);
}